// Round 3
// baseline (437.891 us; speedup 1.0000x reference)
//
#include <hip/hip_runtime.h>
#include <hip/hip_bf16.h>
#include <math.h>

#define MARGIN_F 6.0f
// phase = pr / (REL_RANGE/PI) = pr * (PI / 0.03125)
#define PHASE_SCALE 100.53096491487338f

// ---------------------------------------------------------------------------
// K1: fused prep. grid = 16 blocks (one per b), 1024 threads (16 waves).
//  - mean-pool qh[b] (64x768) -> q[768] in LDS
//  - linear 768->18 + sigmoid (one wave per relation)
//  - mixture -> phase -> sincos -> head gather -> complex rotate
// rot layout in ws: rot_re[16][256] at float offset 0, rot_im at 4096.
// ---------------------------------------------------------------------------
__global__ void k_prep(const float* __restrict__ qh, const float* __restrict__ W,
                       const float* __restrict__ brel,
                       const float* __restrict__ rel,
                       const float* __restrict__ ent, const int* __restrict__ hid,
                       float* __restrict__ rot) {
    __shared__ float q[768];
    __shared__ float sig[18];
    int b = blockIdx.x;
    int t = threadIdx.x;

    if (t < 768) {
        float s = 0.f;
        const float* base = qh + (size_t)b * 64 * 768 + t;
        #pragma unroll 8
        for (int srow = 0; srow < 64; ++srow) s += base[(size_t)srow * 768];
        q[t] = s * (1.0f / 64.0f);
    }
    __syncthreads();

    int wave = t >> 6, lane = t & 63;
    for (int r = wave; r < 18; r += 16) {
        float p = 0.f;
        for (int h = lane; h < 768; h += 64) p += q[h] * W[r * 768 + h];
        for (int off = 32; off; off >>= 1) p += __shfl_xor(p, off, 64);
        if (lane == 0) sig[r] = 1.0f / (1.0f + expf(-(p + brel[r])));
    }
    __syncthreads();

    if (t < 256) {
        int d = t;
        float pr = 0.f;
        #pragma unroll
        for (int r = 0; r < 18; ++r) pr += sig[r] * rel[r * 256 + d];
        float phase = pr * PHASE_SCALE;
        float sn, cs;
        sincosf(phase, &sn, &cs);
        int h0 = hid[b];
        float reh = ent[(size_t)h0 * 512 + d];
        float imh = ent[(size_t)h0 * 512 + 256 + d];
        rot[b * 256 + d]        = reh * cs - imh * sn;  // rot_re
        rot[4096 + b * 256 + d] = reh * sn + imh * cs;  // rot_im
    }
}

// ---------------------------------------------------------------------------
// K2: lane-per-entity distance, d split 8-ways inside the wave.
// lane = s*8 + e  (s = d-eighth 0..7 -> dims s*32..s*32+31, e = entity 0..7).
// Each lane accumulates acc[16] locally over its 32 dims; final reduce over s
// is 3 shuffle+add per b. No per-entity shuffle cascade, no LDS.
// ---------------------------------------------------------------------------
__global__ __launch_bounds__(256, 4) void k_dist(const float* __restrict__ ent,
                                                 const float* __restrict__ rot,
                                                 float* __restrict__ out, int E,
                                                 int NT) {
    int lane = threadIdx.x & 63;
    int tile = blockIdx.x * 4 + (threadIdx.x >> 6);
    if (tile >= NT) return;

    int s = lane >> 3;  // d-eighth
    int e = lane & 7;   // entity within tile
    int ei = tile * 8 + e;
    int eread = ei < E ? ei : (E - 1);

    const float4* row = (const float4*)(ent + (size_t)eread * 512);
    const float4* rre = (const float4*)rot;           // [16][64] float4
    const float4* rim = (const float4*)(rot + 4096);  // [16][64] float4
    int c0 = s * 8;  // float4 index of this lane's d-range start

    float acc[16];
    #pragma unroll
    for (int b = 0; b < 16; ++b) acc[b] = 0.f;

    #pragma unroll
    for (int c = 0; c < 8; ++c) {
        float4 te = row[c0 + c];
        float4 ti = row[64 + c0 + c];
        #pragma unroll
        for (int b = 0; b < 16; ++b) {
            float4 rr = rre[b * 64 + c0 + c];
            float4 ri = rim[b * 64 + c0 + c];
            float dx0 = rr.x - te.x, dy0 = ri.x - ti.x;
            float dx1 = rr.y - te.y, dy1 = ri.y - ti.y;
            float dx2 = rr.z - te.z, dy2 = ri.z - ti.z;
            float dx3 = rr.w - te.w, dy3 = ri.w - ti.w;
            float s0 = __builtin_amdgcn_sqrtf(dx0 * dx0 + dy0 * dy0);
            float s1 = __builtin_amdgcn_sqrtf(dx1 * dx1 + dy1 * dy1);
            float s2 = __builtin_amdgcn_sqrtf(dx2 * dx2 + dy2 * dy2);
            float s3 = __builtin_amdgcn_sqrtf(dx3 * dx3 + dy3 * dy3);
            acc[b] += (s0 + s1) + (s2 + s3);
        }
    }

    // reduce over the 8 d-eighths (lane bits 3..5)
    #pragma unroll
    for (int b = 0; b < 16; ++b) {
        acc[b] += __shfl_xor(acc[b], 8, 64);
        acc[b] += __shfl_xor(acc[b], 16, 64);
        acc[b] += __shfl_xor(acc[b], 32, 64);
    }

    if (s == 0 && ei < E) {
        #pragma unroll
        for (int b = 0; b < 16; ++b) out[(size_t)b * E + ei] = MARGIN_F - acc[b];
    }
}

extern "C" void kernel_launch(void* const* d_in, const int* in_sizes, int n_in,
                              void* d_out, int out_size, void* d_ws,
                              size_t ws_size, hipStream_t stream) {
    const float* qh   = (const float*)d_in[0];  // (16,64,768)
    const float* W    = (const float*)d_in[1];  // (18,768)
    const float* brel = (const float*)d_in[2];  // (18,)
    const float* rel  = (const float*)d_in[3];  // (18,256)
    const float* ent  = (const float*)d_in[4];  // (E,512)
    const int*   hid  = (const int*)d_in[5];    // (16,)
    float* out = (float*)d_out;

    int E = in_sizes[4] / 512;

    float* rot = (float*)d_ws;  // 2*16*256 floats = 32 KB

    k_prep<<<dim3(16), 1024, 0, stream>>>(qh, W, brel, rel, ent, hid, rot);

    int NT = (E + 7) / 8;            // tiles of 8 entities, one wave each
    int nblocks = (NT + 3) / 4;      // 4 waves per block
    k_dist<<<dim3(nblocks), 256, 0, stream>>>(ent, rot, out, E, NT);
}

// Round 4
// 63.180 us; speedup vs baseline: 6.9309x; 6.9309x over previous
//
#include <hip/hip_runtime.h>
#include <hip/hip_bf16.h>
#include <math.h>

#define MARGIN_F 6.0f
// phase = pr / (REL_RANGE/PI) = pr * (PI / 0.03125)
#define PHASE_SCALE 100.53096491487338f

// ---------------------------------------------------------------------------
// K1: fused prep. grid = 16 blocks (one per b), 1024 threads (16 waves).
//  - mean-pool qh[b] (64x768) -> q[768] in LDS
//  - linear 768->18 + sigmoid (one wave per relation)
//  - mixture -> phase -> sincos -> head gather -> complex rotate
// rot layout in ws: rot_re[16][256] at float offset 0, rot_im at 4096.
// ---------------------------------------------------------------------------
__global__ void k_prep(const float* __restrict__ qh, const float* __restrict__ W,
                       const float* __restrict__ brel,
                       const float* __restrict__ rel,
                       const float* __restrict__ ent, const int* __restrict__ hid,
                       float* __restrict__ rot) {
    __shared__ float q[768];
    __shared__ float sig[18];
    int b = blockIdx.x;
    int t = threadIdx.x;

    if (t < 768) {
        float s = 0.f;
        const float* base = qh + (size_t)b * 64 * 768 + t;
        #pragma unroll 8
        for (int srow = 0; srow < 64; ++srow) s += base[(size_t)srow * 768];
        q[t] = s * (1.0f / 64.0f);
    }
    __syncthreads();

    int wave = t >> 6, lane = t & 63;
    for (int r = wave; r < 18; r += 16) {
        float p = 0.f;
        for (int h = lane; h < 768; h += 64) p += q[h] * W[r * 768 + h];
        for (int off = 32; off; off >>= 1) p += __shfl_xor(p, off, 64);
        if (lane == 0) sig[r] = 1.0f / (1.0f + expf(-(p + brel[r])));
    }
    __syncthreads();

    if (t < 256) {
        int d = t;
        float pr = 0.f;
        #pragma unroll
        for (int r = 0; r < 18; ++r) pr += sig[r] * rel[r * 256 + d];
        float phase = pr * PHASE_SCALE;
        float sn, cs;
        sincosf(phase, &sn, &cs);
        int h0 = hid[b];
        float reh = ent[(size_t)h0 * 512 + d];
        float imh = ent[(size_t)h0 * 512 + 256 + d];
        rot[b * 256 + d]        = reh * cs - imh * sn;  // rot_re
        rot[4096 + b * 256 + d] = reh * sn + imh * cs;  // rot_im
    }
}

// ---------------------------------------------------------------------------
// K2: wave-per-entity, 8 batch-rows per wave (pair of waves covers b=0..15).
// lane l owns dims 4l..4l+3 -> entity row read as 2 fully-coalesced float4
// loads (1 KB/instr). rot fragments for 8 b's = 64 VGPR, honestly resident.
// Reduction: 10-shuffle compaction (4-deep chain) per entity.
// ---------------------------------------------------------------------------
__global__ __launch_bounds__(256, 4) void k_dist(const float* __restrict__ ent,
                                                 const float* __restrict__ rot,
                                                 float* __restrict__ out, int E,
                                                 int chunk) {
    int lane = threadIdx.x & 63;
    int wid = blockIdx.x * 4 + (threadIdx.x >> 6);
    int bhalf = wid & 1;       // which 8 b's this wave owns
    int pair = wid >> 1;       // entity-chunk index

    const float4* rre4 = (const float4*)rot + (size_t)bhalf * 8 * 64;
    const float4* rim4 = (const float4*)(rot + 4096) + (size_t)bhalf * 8 * 64;
    float4 rre[8], rim[8];
    #pragma unroll
    for (int b = 0; b < 8; ++b) {
        rre[b] = rre4[b * 64 + lane];
        rim[b] = rim4[b * 64 + lane];
    }

    // b owned by lane l (<8) after compaction: bits (l0->b2, l1->b1, l2->b0)
    int bout = bhalf * 8 + ((lane & 1) << 2) | (lane & 2) | ((lane >> 2) & 1);
    // note: | binds lower than +, parenthesize properly below
    bout = bhalf * 8 + (((lane & 1) << 2) | (lane & 2) | ((lane >> 2) & 1));

    int e0 = (int)((long long)pair * chunk);
    int e1 = min(e0 + chunk, E);
    if (e0 >= e1) return;

    const float4* r4 = (const float4*)(ent + (size_t)e0 * 512);
    float4 te = r4[lane];
    float4 ti = r4[64 + lane];

    for (int e = e0; e < e1; ++e) {
        float4 nte = make_float4(0.f, 0.f, 0.f, 0.f);
        float4 nti = nte;
        if (e + 1 < e1) {  // prefetch next entity row
            const float4* n4 = (const float4*)(ent + (size_t)(e + 1) * 512);
            nte = n4[lane];
            nti = n4[64 + lane];
        }

        float v[8];
        #pragma unroll
        for (int b = 0; b < 8; ++b) {
            float dx0 = rre[b].x - te.x, dy0 = rim[b].x - ti.x;
            float dx1 = rre[b].y - te.y, dy1 = rim[b].y - ti.y;
            float dx2 = rre[b].z - te.z, dy2 = rim[b].z - ti.z;
            float dx3 = rre[b].w - te.w, dy3 = rim[b].w - ti.w;
            float s0 = __builtin_amdgcn_sqrtf(dx0 * dx0 + dy0 * dy0);
            float s1 = __builtin_amdgcn_sqrtf(dx1 * dx1 + dy1 * dy1);
            float s2 = __builtin_amdgcn_sqrtf(dx2 * dx2 + dy2 * dy2);
            float s3 = __builtin_amdgcn_sqrtf(dx3 * dx3 + dy3 * dy3);
            v[b] = (s0 + s1) + (s2 + s3);
        }

        // compaction reduce: 8 values x 64 lanes -> 1 value on lanes 0..7
        #pragma unroll
        for (int i = 0; i < 4; ++i) {
            float send = (lane & 1) ? v[i] : v[i + 4];
            float recv = __shfl_xor(send, 1, 64);
            v[i] = ((lane & 1) ? v[i + 4] : v[i]) + recv;
        }
        #pragma unroll
        for (int i = 0; i < 2; ++i) {
            float send = (lane & 2) ? v[i] : v[i + 2];
            float recv = __shfl_xor(send, 2, 64);
            v[i] = ((lane & 2) ? v[i + 2] : v[i]) + recv;
        }
        {
            float send = (lane & 4) ? v[0] : v[1];
            float recv = __shfl_xor(send, 4, 64);
            v[0] = ((lane & 4) ? v[1] : v[0]) + recv;
        }
        v[0] += __shfl_xor(v[0], 8, 64);
        v[0] += __shfl_xor(v[0], 16, 64);
        v[0] += __shfl_xor(v[0], 32, 64);

        if (lane < 8) out[(size_t)bout * E + e] = MARGIN_F - v[0];

        te = nte;
        ti = nti;
    }
}

extern "C" void kernel_launch(void* const* d_in, const int* in_sizes, int n_in,
                              void* d_out, int out_size, void* d_ws,
                              size_t ws_size, hipStream_t stream) {
    const float* qh   = (const float*)d_in[0];  // (16,64,768)
    const float* W    = (const float*)d_in[1];  // (18,768)
    const float* brel = (const float*)d_in[2];  // (18,)
    const float* rel  = (const float*)d_in[3];  // (18,256)
    const float* ent  = (const float*)d_in[4];  // (E,512)
    const int*   hid  = (const int*)d_in[5];    // (16,)
    float* out = (float*)d_out;

    int E = in_sizes[4] / 512;

    float* rot = (float*)d_ws;  // 2*16*256 floats = 32 KB

    k_prep<<<dim3(16), 1024, 0, stream>>>(qh, W, brel, rel, ent, hid, rot);

    const int NB = 1024;               // 4096 waves = 2048 wave-pairs
    int npairs = NB * 4 / 2;
    int chunk = (E + npairs - 1) / npairs;  // ~22 consecutive entities/pair
    k_dist<<<dim3(NB), 256, 0, stream>>>(ent, rot, out, E, chunk);
}